// Round 6
// baseline (431.740 us; speedup 1.0000x reference)
//
#include <hip/hip_runtime.h>
#include <cstddef>
#include <cstdint>

#define NN 20000
#define SDIM 256

typedef short frag16 __attribute__((ext_vector_type(8)));
typedef float f32x4 __attribute__((ext_vector_type(4)));

__device__ inline unsigned short f32_to_bf16(float f) {
    uint32_t u = __float_as_uint(f);
    u += 0x7FFFu + ((u >> 16) & 1u);
    return (unsigned short)(u >> 16);
}

__device__ inline float4 dec4(uint2 v) {
    float4 r;
    r.x = __uint_as_float(v.x << 16);
    r.y = __uint_as_float(v.x & 0xffff0000u);
    r.z = __uint_as_float(v.y << 16);
    r.w = __uint_as_float(v.y & 0xffff0000u);
    return r;
}

// ---------------- nsum bf16: rows >= NN zeroed (pad to 20096) ----------------
__global__ void nsum_b16(const float* __restrict__ nodes, unsigned short* __restrict__ out) {
    int idx = blockIdx.x * 256 + threadIdx.x;     // quad index, 20096*128 total
    int n = idx >> 7, k4 = (idx & 127) << 2;
    uint2 o;
    if (n < NN) {
        float4 a = *(const float4*)(nodes + (size_t)n * 1024 + k4);
        float4 b = *(const float4*)(nodes + (size_t)n * 1024 + 512 + k4);
        o.x = ((uint32_t)f32_to_bf16(a.y + b.y) << 16) | f32_to_bf16(a.x + b.x);
        o.y = ((uint32_t)f32_to_bf16(a.w + b.w) << 16) | f32_to_bf16(a.z + b.z);
    } else { o.x = 0; o.y = 0; }
    *(uint2*)(out + (size_t)idx * 4) = o;
}

// ---------------- fp32 -> bf16, 4 elems/thread ----------------
__global__ void tob16v(const float* __restrict__ in, unsigned short* __restrict__ out) {
    int i = blockIdx.x * 256 + threadIdx.x;
    float4 v = *(const float4*)(in + (size_t)i * 4);
    uint2 o;
    o.x = ((uint32_t)f32_to_bf16(v.y) << 16) | f32_to_bf16(v.x);
    o.y = ((uint32_t)f32_to_bf16(v.w) << 16) | f32_to_bf16(v.z);
    *(uint2*)(out + (size_t)i * 4) = o;
}

// ---------------- tiled transpose f32 -> bf16: out[l][c][r] = in[l][r][c] ----------------
__global__ __launch_bounds__(256) void transp_b16(const float* __restrict__ in,
                                                  unsigned short* __restrict__ out,
                                                  int R, int C) {
    __shared__ unsigned short t[64][68];
    const float* inp = in + (size_t)blockIdx.z * R * C;
    unsigned short* outp = out + (size_t)blockIdx.z * R * C;
    int r0 = blockIdx.y * 64, c0 = blockIdx.x * 64;
    int tx = threadIdx.x & 15, ty = threadIdx.x >> 4;
    #pragma unroll
    for (int rr = 0; rr < 4; ++rr) {
        int r = ty * 4 + rr;
        float4 v = *(const float4*)(inp + (size_t)(r0 + r) * C + c0 + tx * 4);
        t[tx * 4 + 0][r] = f32_to_bf16(v.x);
        t[tx * 4 + 1][r] = f32_to_bf16(v.y);
        t[tx * 4 + 2][r] = f32_to_bf16(v.z);
        t[tx * 4 + 3][r] = f32_to_bf16(v.w);
    }
    __syncthreads();
    #pragma unroll
    for (int cc = 0; cc < 4; ++cc) {
        int c = ty * 4 + cc;
        ushort4 o = *(ushort4*)&t[c][tx * 4];
        *(ushort4*)(outp + (size_t)(c0 + c) * R + r0 + tx * 4) = o;
    }
}

// ---------------- c[b,s] = 2 * dot(x[b,s,:], bp) ----------------
__global__ void cvec_kernel(const float* __restrict__ x, const float* __restrict__ bp,
                            float* __restrict__ c) {
    int row = blockIdx.x * 4 + (threadIdx.x >> 6);
    int lane = threadIdx.x & 63;
    const float* xr = x + (size_t)row * 512;
    float s = 0.f;
    #pragma unroll
    for (int k = 0; k < 512; k += 64) s += xr[k + lane] * bp[k + lane];
    #pragma unroll
    for (int off = 32; off; off >>= 1) s += __shfl_down(s, off);
    if (lane == 0) c[row] = 2.0f * s;
}

__global__ void count_kernel(const int* __restrict__ dst, int* __restrict__ cnt, int E) {
    int e = blockIdx.x * 256 + threadIdx.x;
    if (e < E) atomicAdd(&cnt[dst[e]], 1);
}

// ---------------- single-block exclusive scan + dinv, 4 elems/thread ----------------
__global__ __launch_bounds__(1024) void scan_kernel(const int* __restrict__ cnt,
                                                    int* __restrict__ offs,
                                                    float* __restrict__ dinv, int n) {
    __shared__ int wsum[16];
    __shared__ int s_carry;
    int tid = threadIdx.x, lane = tid & 63, wid = tid >> 6;
    if (tid == 0) s_carry = 0;
    __syncthreads();
    for (int base = 0; base < n; base += 4096) {
        int i4 = base + tid * 4;
        int4 v = make_int4(0, 0, 0, 0);
        if (i4 < n) v = *(const int4*)(cnt + i4);
        int tsum = v.x + v.y + v.z + v.w;
        int x = tsum;
        #pragma unroll
        for (int off = 1; off < 64; off <<= 1) {
            int t = __shfl_up(x, off);
            if (lane >= off) x += t;
        }
        if (lane == 63) wsum[wid] = x;
        __syncthreads();
        if (wid == 0) {
            int wv = (lane < 16) ? wsum[lane] : 0;
            int wy = wv;
            #pragma unroll
            for (int off = 1; off < 16; off <<= 1) {
                int t = __shfl_up(wy, off);
                if (lane >= off) wy += t;
            }
            if (lane < 16) wsum[lane] = wy - wv;
        }
        __syncthreads();
        int excl = s_carry + wsum[wid] + x - tsum;
        if (i4 < n) {
            offs[i4 + 0] = excl;
            offs[i4 + 1] = excl + v.x;
            offs[i4 + 2] = excl + v.x + v.y;
            offs[i4 + 3] = excl + v.x + v.y + v.z;
            float4 d;
            d.x = rsqrtf((float)(v.x + 1)); d.y = rsqrtf((float)(v.y + 1));
            d.z = rsqrtf((float)(v.z + 1)); d.w = rsqrtf((float)(v.w + 1));
            *(float4*)(dinv + i4) = d;
        }
        __syncthreads();
        if (tid == 1023) s_carry = excl + tsum;
        __syncthreads();
    }
    if (threadIdx.x == 0) offs[n] = s_carry;
}

__global__ void fill_kernel(const int* __restrict__ src, const int* __restrict__ dst,
                            const int* __restrict__ offs, int* __restrict__ cursor,
                            int* __restrict__ csr, int E) {
    int e = blockIdx.x * 256 + threadIdx.x;
    if (e < E) {
        int d = dst[e];
        int pos = atomicAdd(&cursor[d], 1);
        csr[offs[d] + pos] = src[e];
    }
}

// ---------------- bf16 MFMA GEMM (m97-style gemm_bt) ----------------
// C[M,N] = A[M,K] @ BT[N,K]^T, bf16 in / bf16 out, fp32 accum.
// mode 0: C[m*N+n] = acc
// mode 1: h0-fused: b=n>>8, s=n&255; C[(b*NN+m)*256+s] = acc + colbias[n]; store iff m<NN||b
// mode 2: N=256; b=m>=NN, node=m-b*NN; C[node*512 + b*256 + n] = acc * dinv[node]
__global__ __launch_bounds__(256) void mgemm(
    const unsigned short* __restrict__ A, const unsigned short* __restrict__ BT,
    int K, int N, int mode,
    const float* __restrict__ colbias, const float* __restrict__ dinv,
    unsigned short* __restrict__ C)
{
    __shared__ __align__(16) unsigned short As[128 * 32];
    __shared__ __align__(16) unsigned short Bs[128 * 32];
    const int bm = blockIdx.y * 128, bn = blockIdx.x * 128;
    const int tid = threadIdx.x;
    const int lane = tid & 63, w = tid >> 6;
    const int wm = (w >> 1) << 6, wn = (w & 1) << 6;
    const int r = lane & 15, q = lane >> 4;

    f32x4 acc[4][4] = {};

    for (int k0 = 0; k0 < K; k0 += 32) {
        __syncthreads();
        #pragma unroll
        for (int t = 0; t < 2; ++t) {
            int c = t * 256 + w * 64 + lane;
            int row = c >> 2, col = (c & 3) << 3;
            __builtin_amdgcn_global_load_lds(
                (const __attribute__((address_space(1))) void*)(A + (size_t)(bm + row) * K + k0 + col),
                (__attribute__((address_space(3))) void*)(As + (size_t)(t * 256 + w * 64) * 8),
                16, 0, 0);
            __builtin_amdgcn_global_load_lds(
                (const __attribute__((address_space(1))) void*)(BT + (size_t)(bn + row) * K + k0 + col),
                (__attribute__((address_space(3))) void*)(Bs + (size_t)(t * 256 + w * 64) * 8),
                16, 0, 0);
        }
        __syncthreads();
        frag16 af[4], bf[4];
        #pragma unroll
        for (int i = 0; i < 4; ++i)
            af[i] = *(const frag16*)(As + ((wm + i * 16 + r) << 5) + (q << 3));
        #pragma unroll
        for (int j = 0; j < 4; ++j)
            bf[j] = *(const frag16*)(Bs + ((wn + j * 16 + r) << 5) + (q << 3));
        #pragma unroll
        for (int i = 0; i < 4; ++i)
            #pragma unroll
            for (int j = 0; j < 4; ++j)
                acc[i][j] = __builtin_amdgcn_mfma_f32_16x16x32_bf16(af[i], bf[j], acc[i][j], 0, 0, 0);
    }

    // C/D layout: col = lane&15 (r), row = q*4 + reg
    #pragma unroll
    for (int i = 0; i < 4; ++i) {
        #pragma unroll
        for (int rg = 0; rg < 4; ++rg) {
            int m = bm + wm + i * 16 + (q << 2) + rg;
            float sc = 1.0f;
            int b2 = 0, node = m;
            if (mode == 2) {
                b2 = m >= NN;
                node = m - b2 * NN;
                sc = dinv[node < NN ? node : NN - 1];
                if (node > 20095) node = 20095;   // pad rows: in-bounds garbage
            }
            #pragma unroll
            for (int j = 0; j < 4; ++j) {
                int n = bn + wn + j * 16 + r;
                float v = acc[i][j][rg] * sc;
                if (mode == 1) {
                    int b = n >> 8;
                    if (m < NN || b) {
                        v += colbias[n];
                        C[((size_t)(b * NN + m)) * 256 + (n & 255)] = f32_to_bf16(v);
                    }
                } else if (mode == 2) {
                    C[(size_t)node * 512 + (b2 << 8) + n] = f32_to_bf16(v);
                } else {
                    C[(size_t)m * N + n] = f32_to_bf16(v);
                }
            }
        }
    }
}

// ---------------- GCN aggregation: one wave per node, BOTH batches (interleaved hw) ----
// hw: [20096][512] bf16, cols 0..255 = b0, 256..511 = b1, pre-scaled by dinv[src].
__global__ __launch_bounds__(256) void aggregate_i(
    const unsigned short* __restrict__ hw, const int* __restrict__ offs,
    const int* __restrict__ csr, const float* __restrict__ dinv,
    const float* __restrict__ bias, unsigned short* __restrict__ hout,
    const float* __restrict__ w_bp, const float* __restrict__ b_bp,
    float* __restrict__ out)
{
    int n = blockIdx.x * 4 + (threadIdx.x >> 6);   // node 0..19999
    int lane = threadIdx.x & 63;
    const unsigned short* rowp = hw + (lane << 3);

    float acc[8];
    {
        uint4 u = *(const uint4*)(rowp + (size_t)n * 512);
        float4 a = dec4(make_uint2(u.x, u.y)), b = dec4(make_uint2(u.z, u.w));
        acc[0] = a.x; acc[1] = a.y; acc[2] = a.z; acc[3] = a.w;
        acc[4] = b.x; acc[5] = b.y; acc[6] = b.z; acc[7] = b.w;
    }
    int e0 = offs[n], e1 = offs[n + 1];
    int e = e0;
    for (; e + 4 <= e1; e += 4) {
        int s0 = csr[e + 0], s1 = csr[e + 1], s2 = csr[e + 2], s3 = csr[e + 3];
        uint4 u0 = *(const uint4*)(rowp + (size_t)s0 * 512);
        uint4 u1 = *(const uint4*)(rowp + (size_t)s1 * 512);
        uint4 u2 = *(const uint4*)(rowp + (size_t)s2 * 512);
        uint4 u3 = *(const uint4*)(rowp + (size_t)s3 * 512);
        float4 a0 = dec4(make_uint2(u0.x, u0.y)), b0 = dec4(make_uint2(u0.z, u0.w));
        float4 a1 = dec4(make_uint2(u1.x, u1.y)), b1 = dec4(make_uint2(u1.z, u1.w));
        float4 a2 = dec4(make_uint2(u2.x, u2.y)), b2 = dec4(make_uint2(u2.z, u2.w));
        float4 a3 = dec4(make_uint2(u3.x, u3.y)), b3 = dec4(make_uint2(u3.z, u3.w));
        acc[0] += (a0.x + a1.x) + (a2.x + a3.x);
        acc[1] += (a0.y + a1.y) + (a2.y + a3.y);
        acc[2] += (a0.z + a1.z) + (a2.z + a3.z);
        acc[3] += (a0.w + a1.w) + (a2.w + a3.w);
        acc[4] += (b0.x + b1.x) + (b2.x + b3.x);
        acc[5] += (b0.y + b1.y) + (b2.y + b3.y);
        acc[6] += (b0.z + b1.z) + (b2.z + b3.z);
        acc[7] += (b0.w + b1.w) + (b2.w + b3.w);
    }
    for (; e < e1; ++e) {
        uint4 u = *(const uint4*)(rowp + (size_t)csr[e] * 512);
        float4 a = dec4(make_uint2(u.x, u.y)), b = dec4(make_uint2(u.z, u.w));
        acc[0] += a.x; acc[1] += a.y; acc[2] += a.z; acc[3] += a.w;
        acc[4] += b.x; acc[5] += b.y; acc[6] += b.z; acc[7] += b.w;
    }

    float dn = dinv[n];
    int s = (lane & 31) << 3;                  // channel base within batch
    float4 bl0 = *(const float4*)(bias + s);
    float4 bl1 = *(const float4*)(bias + s + 4);
    float v[8];
    v[0] = fmaf(dn, acc[0], bl0.x); v[1] = fmaf(dn, acc[1], bl0.y);
    v[2] = fmaf(dn, acc[2], bl0.z); v[3] = fmaf(dn, acc[3], bl0.w);
    v[4] = fmaf(dn, acc[4], bl1.x); v[5] = fmaf(dn, acc[5], bl1.y);
    v[6] = fmaf(dn, acc[6], bl1.z); v[7] = fmaf(dn, acc[7], bl1.w);
    #pragma unroll
    for (int j = 0; j < 8; ++j) v[j] = v[j] > 0.f ? v[j] : 0.01f * v[j];

    int b = lane >> 5;                          // 0: batch0 half, 1: batch1 half
    if (out) {
        float4 w0 = *(const float4*)(w_bp + s);
        float4 w1 = *(const float4*)(w_bp + s + 4);
        float sum = v[0] * w0.x + v[1] * w0.y + v[2] * w0.z + v[3] * w0.w
                  + v[4] * w1.x + v[5] * w1.y + v[6] * w1.z + v[7] * w1.w;
        #pragma unroll
        for (int off = 16; off; off >>= 1) sum += __shfl_xor(sum, off);  // half-wave reduce
        if ((lane & 31) == 0) out[b * NN + n] = sum + b_bp[0];
    } else {
        uint4 o;
        o.x = ((uint32_t)f32_to_bf16(v[1]) << 16) | f32_to_bf16(v[0]);
        o.y = ((uint32_t)f32_to_bf16(v[3]) << 16) | f32_to_bf16(v[2]);
        o.z = ((uint32_t)f32_to_bf16(v[5]) << 16) | f32_to_bf16(v[4]);
        o.w = ((uint32_t)f32_to_bf16(v[7]) << 16) | f32_to_bf16(v[6]);
        *(uint4*)(hout + ((size_t)(b * NN + n)) * 256 + s) = o;
    }
}

extern "C" void kernel_launch(void* const* d_in, const int* in_sizes, int n_in,
                              void* d_out, int out_size, void* d_ws, size_t ws_size,
                              hipStream_t stream) {
    const float* x     = (const float*)d_in[0];
    const float* nodes = (const float*)d_in[1];
    const int*   eidx  = (const int*)d_in[2];
    const float* Wp    = (const float*)d_in[3];
    const float* bp    = (const float*)d_in[4];
    const float* gcn_W = (const float*)d_in[5];
    const float* gcn_b = (const float*)d_in[6];
    const float* w_bp  = (const float*)d_in[7];
    const float* b_bp  = (const float*)d_in[8];
    const int E = in_sizes[2] / 2;
    const int N = NN;

    char* w = (char*)d_ws;
    auto alloc = [&](size_t bytes) { char* p = w; w += (bytes + 255) & ~(size_t)255; return p; };
    unsigned short* nsum16 = (unsigned short*)alloc((size_t)20096 * 512 * 2); // reused as hw16
    unsigned short* hA     = (unsigned short*)alloc((size_t)40192 * 256 * 2);
    unsigned short* hB     = (unsigned short*)alloc((size_t)40192 * 256 * 2);
    unsigned short* xb  = (unsigned short*)alloc((size_t)512 * 512 * 2);
    unsigned short* WpT = (unsigned short*)alloc((size_t)512 * 512 * 2);
    unsigned short* yb  = (unsigned short*)alloc((size_t)512 * 512 * 2);
    unsigned short* WT  = (unsigned short*)alloc((size_t)3 * 256 * 256 * 2);
    float* cvec = (float*)alloc(512 * 4);
    float* dinv = (float*)alloc((size_t)N * 4);
    int*   cnt    = (int*)alloc((size_t)N * 4);
    int*   offs   = (int*)alloc((size_t)(N + 1) * 4);
    int*   cursor = (int*)alloc((size_t)N * 4);
    int*   csr    = (int*)alloc((size_t)E * 4);
    unsigned short* hw16 = nsum16;   // alias: nsum dead after h0 GEMM

    hipMemsetAsync(cnt, 0, (size_t)N * 4, stream);
    hipMemsetAsync(cursor, 0, (size_t)N * 4, stream);

    nsum_b16<<<10048, 256, 0, stream>>>(nodes, nsum16);
    tob16v<<<256, 256, 0, stream>>>(x, xb);
    transp_b16<<<dim3(8, 8, 1), 256, 0, stream>>>(Wp, WpT, 512, 512);
    transp_b16<<<dim3(4, 4, 3), 256, 0, stream>>>(gcn_W, WT, 256, 256);
    cvec_kernel<<<128, 256, 0, stream>>>(x, bp, cvec);
    count_kernel<<<(E + 255) / 256, 256, 0, stream>>>(eidx + E, cnt, E);
    scan_kernel<<<1, 1024, 0, stream>>>(cnt, offs, dinv, N);
    fill_kernel<<<(E + 255) / 256, 256, 0, stream>>>(eidx, eidx + E, offs, cursor, csr, E);

    // y[bs, j] = sum_k x[bs,k] Wp[k,j]
    mgemm<<<dim3(4, 4), 256, 0, stream>>>(xb, WpT, 512, 512, 0, nullptr, nullptr, yb);

    // h0: single fused GEMM over both batches
    mgemm<<<dim3(4, 157), 256, 0, stream>>>(nsum16, yb, 512, 512, 1, cvec, nullptr, hA);

    unsigned short* hin = hA;
    unsigned short* hout = hB;
    for (int l = 0; l < 3; ++l) {
        mgemm<<<dim3(2, 313), 256, 0, stream>>>(
            hin, WT + (size_t)l * 256 * 256, 256, 256, 2, nullptr, dinv, hw16);
        bool last = (l == 2);
        aggregate_i<<<5000, 256, 0, stream>>>(
            hw16, offs, csr, dinv, gcn_b + l * 256,
            last ? nullptr : hout, w_bp, b_bp,
            last ? (float*)d_out : nullptr);
        unsigned short* t = hin; hin = hout; hout = t;
    }
}

// Round 7
// 427.752 us; speedup vs baseline: 1.0093x; 1.0093x over previous
//
#include <hip/hip_runtime.h>
#include <cstddef>
#include <cstdint>

#define NN 20000
#define SDIM 256

typedef short frag16 __attribute__((ext_vector_type(8)));
typedef float f32x4 __attribute__((ext_vector_type(4)));

__device__ inline unsigned short f32_to_bf16(float f) {
    uint32_t u = __float_as_uint(f);
    u += 0x7FFFu + ((u >> 16) & 1u);
    return (unsigned short)(u >> 16);
}

__device__ inline float4 dec4(uint2 v) {
    float4 r;
    r.x = __uint_as_float(v.x << 16);
    r.y = __uint_as_float(v.x & 0xffff0000u);
    r.z = __uint_as_float(v.y << 16);
    r.w = __uint_as_float(v.y & 0xffff0000u);
    return r;
}

// ============ fused prep: nsum | x,Wp->bf16 | gcn_W transpose | cvec | count =========
// grid sections (256 threads each):
//   [0,10048)        nsum_b16  (20096x512, pad rows zero)
//   [10048,10304)    cast x (262144 el) then Wp (262144 el) -> bf16, 8 el/thread
//   [10304,10352)    transpose gcn_W -> WT (3 x 256x256, 64x64 tiles)
//   [10352,10480)    cvec: c[bs] = 2*dot(x[bs,:],bp)
//   [10480,...)      count: atomicAdd(cnt[dst[e]])
__global__ __launch_bounds__(256) void prep(
    const float* __restrict__ nodes, const float* __restrict__ x,
    const float* __restrict__ Wp, const float* __restrict__ gcn_W,
    const float* __restrict__ bp, const int* __restrict__ dst,
    unsigned short* __restrict__ nsum16, unsigned short* __restrict__ xb,
    unsigned short* __restrict__ Wpb, unsigned short* __restrict__ WT,
    float* __restrict__ cvec, int* __restrict__ cnt, int E)
{
    __shared__ unsigned short tsh[64][68];
    const int blk = blockIdx.x, tid = threadIdx.x;

    if (blk < 10048) {                      // ---- nsum ----
        int idx = blk * 256 + tid;          // quad index
        int n = idx >> 7, k4 = (idx & 127) << 2;
        uint2 o;
        if (n < NN) {
            float4 a = *(const float4*)(nodes + (size_t)n * 1024 + k4);
            float4 b = *(const float4*)(nodes + (size_t)n * 1024 + 512 + k4);
            o.x = ((uint32_t)f32_to_bf16(a.y + b.y) << 16) | f32_to_bf16(a.x + b.x);
            o.y = ((uint32_t)f32_to_bf16(a.w + b.w) << 16) | f32_to_bf16(a.z + b.z);
        } else { o.x = 0; o.y = 0; }
        *(uint2*)(nsum16 + (size_t)idx * 4) = o;
    } else if (blk < 10304) {               // ---- casts (x then Wp) ----
        int j = (blk - 10048) * 256 + tid;  // 8-elem chunk id, [0,65536)
        size_t base = (size_t)j * 8;
        const float* src; unsigned short* dstp; size_t off;
        if (base < 262144) { src = x;  dstp = xb;  off = base; }
        else               { src = Wp; dstp = Wpb; off = base - 262144; }
        float4 a = *(const float4*)(src + off);
        float4 b = *(const float4*)(src + off + 4);
        uint4 o;
        o.x = ((uint32_t)f32_to_bf16(a.y) << 16) | f32_to_bf16(a.x);
        o.y = ((uint32_t)f32_to_bf16(a.w) << 16) | f32_to_bf16(a.z);
        o.z = ((uint32_t)f32_to_bf16(b.y) << 16) | f32_to_bf16(b.x);
        o.w = ((uint32_t)f32_to_bf16(b.w) << 16) | f32_to_bf16(b.z);
        *(uint4*)(dstp + off) = o;
    } else if (blk < 10352) {               // ---- gcn_W transpose ----
        int t = blk - 10304;                // [0,48)
        int l = t >> 4, rem = t & 15;
        int c0 = (rem & 3) * 64, r0 = (rem >> 2) * 64;
        const float* inp = gcn_W + (size_t)l * 65536;
        unsigned short* outp = WT + (size_t)l * 65536;
        int tx = tid & 15, ty = tid >> 4;
        #pragma unroll
        for (int rr = 0; rr < 4; ++rr) {
            int r = ty * 4 + rr;
            float4 v = *(const float4*)(inp + (size_t)(r0 + r) * 256 + c0 + tx * 4);
            tsh[tx * 4 + 0][r] = f32_to_bf16(v.x);
            tsh[tx * 4 + 1][r] = f32_to_bf16(v.y);
            tsh[tx * 4 + 2][r] = f32_to_bf16(v.z);
            tsh[tx * 4 + 3][r] = f32_to_bf16(v.w);
        }
        __syncthreads();
        #pragma unroll
        for (int cc = 0; cc < 4; ++cc) {
            int c = ty * 4 + cc;
            ushort4 o = *(ushort4*)&tsh[c][tx * 4];
            *(ushort4*)(outp + (size_t)(c0 + c) * 256 + r0 + tx * 4) = o;
        }
    } else if (blk < 10480) {               // ---- cvec ----
        int row = (blk - 10352) * 4 + (tid >> 6);
        int lane = tid & 63;
        const float* xr = x + (size_t)row * 512;
        float s = 0.f;
        #pragma unroll
        for (int k = 0; k < 512; k += 64) s += xr[k + lane] * bp[k + lane];
        #pragma unroll
        for (int off = 32; off; off >>= 1) s += __shfl_down(s, off);
        if (lane == 0) cvec[row] = 2.0f * s;
    } else {                                // ---- degree count ----
        int e = (blk - 10480) * 256 + tid;
        if (e < E) atomicAdd(&cnt[dst[e]], 1);
    }
}

// ---------------- single-block exclusive scan + dinv, 4 elems/thread ----------------
__global__ __launch_bounds__(1024) void scan_kernel(const int* __restrict__ cnt,
                                                    int* __restrict__ offs,
                                                    float* __restrict__ dinv, int n) {
    __shared__ int wsum[16];
    __shared__ int s_carry;
    int tid = threadIdx.x, lane = tid & 63, wid = tid >> 6;
    if (tid == 0) s_carry = 0;
    __syncthreads();
    for (int base = 0; base < n; base += 4096) {
        int i4 = base + tid * 4;
        int4 v = make_int4(0, 0, 0, 0);
        if (i4 < n) v = *(const int4*)(cnt + i4);
        int tsum = v.x + v.y + v.z + v.w;
        int x = tsum;
        #pragma unroll
        for (int off = 1; off < 64; off <<= 1) {
            int t = __shfl_up(x, off);
            if (lane >= off) x += t;
        }
        if (lane == 63) wsum[wid] = x;
        __syncthreads();
        if (wid == 0) {
            int wv = (lane < 16) ? wsum[lane] : 0;
            int wy = wv;
            #pragma unroll
            for (int off = 1; off < 16; off <<= 1) {
                int t = __shfl_up(wy, off);
                if (lane >= off) wy += t;
            }
            if (lane < 16) wsum[lane] = wy - wv;
        }
        __syncthreads();
        int excl = s_carry + wsum[wid] + x - tsum;
        if (i4 < n) {
            offs[i4 + 0] = excl;
            offs[i4 + 1] = excl + v.x;
            offs[i4 + 2] = excl + v.x + v.y;
            offs[i4 + 3] = excl + v.x + v.y + v.z;
            float4 d;
            d.x = rsqrtf((float)(v.x + 1)); d.y = rsqrtf((float)(v.y + 1));
            d.z = rsqrtf((float)(v.z + 1)); d.w = rsqrtf((float)(v.w + 1));
            *(float4*)(dinv + i4) = d;
        }
        __syncthreads();
        if (tid == 1023) s_carry = excl + tsum;
        __syncthreads();
    }
    if (threadIdx.x == 0) offs[n] = s_carry;
}

__global__ void fill_kernel(const int* __restrict__ src, const int* __restrict__ dst,
                            const int* __restrict__ offs, int* __restrict__ cursor,
                            int* __restrict__ csr, int E) {
    int e = blockIdx.x * 256 + threadIdx.x;
    if (e < E) {
        int d = dst[e];
        int pos = atomicAdd(&cursor[d], 1);
        csr[offs[d] + pos] = src[e];
    }
}

// ---------------- bf16 MFMA GEMM (m97-style gemm_bt) ----------------
// C[M,N] = A[M,K] @ BT[N,K]^T, bf16 in / bf16 out, fp32 accum.
// mode 0: C[m*N+n] = acc
// mode 1: h0-fused: b=n>>8, s=n&255; C[(b*NN+m)*256+s] = acc + colbias[n]; store iff m<NN||b
// mode 2: N=256; b=m>=NN, node=m-b*NN; C[node*512 + b*256 + n] = acc * dinv[node]
__global__ __launch_bounds__(256) void mgemm(
    const unsigned short* __restrict__ A, const unsigned short* __restrict__ BT,
    int K, int N, int mode,
    const float* __restrict__ colbias, const float* __restrict__ dinv,
    unsigned short* __restrict__ C)
{
    __shared__ __align__(16) unsigned short As[128 * 32];
    __shared__ __align__(16) unsigned short Bs[128 * 32];
    const int bm = blockIdx.y * 128, bn = blockIdx.x * 128;
    const int tid = threadIdx.x;
    const int lane = tid & 63, w = tid >> 6;
    const int wm = (w >> 1) << 6, wn = (w & 1) << 6;
    const int r = lane & 15, q = lane >> 4;

    f32x4 acc[4][4] = {};

    for (int k0 = 0; k0 < K; k0 += 32) {
        __syncthreads();
        #pragma unroll
        for (int t = 0; t < 2; ++t) {
            int c = t * 256 + w * 64 + lane;
            int row = c >> 2, col = (c & 3) << 3;
            __builtin_amdgcn_global_load_lds(
                (const __attribute__((address_space(1))) void*)(A + (size_t)(bm + row) * K + k0 + col),
                (__attribute__((address_space(3))) void*)(As + (size_t)(t * 256 + w * 64) * 8),
                16, 0, 0);
            __builtin_amdgcn_global_load_lds(
                (const __attribute__((address_space(1))) void*)(BT + (size_t)(bn + row) * K + k0 + col),
                (__attribute__((address_space(3))) void*)(Bs + (size_t)(t * 256 + w * 64) * 8),
                16, 0, 0);
        }
        __syncthreads();
        frag16 af[4], bf[4];
        #pragma unroll
        for (int i = 0; i < 4; ++i)
            af[i] = *(const frag16*)(As + ((wm + i * 16 + r) << 5) + (q << 3));
        #pragma unroll
        for (int j = 0; j < 4; ++j)
            bf[j] = *(const frag16*)(Bs + ((wn + j * 16 + r) << 5) + (q << 3));
        #pragma unroll
        for (int i = 0; i < 4; ++i)
            #pragma unroll
            for (int j = 0; j < 4; ++j)
                acc[i][j] = __builtin_amdgcn_mfma_f32_16x16x32_bf16(af[i], bf[j], acc[i][j], 0, 0, 0);
    }

    // C/D layout: col = lane&15 (r), row = q*4 + reg
    #pragma unroll
    for (int i = 0; i < 4; ++i) {
        #pragma unroll
        for (int rg = 0; rg < 4; ++rg) {
            int m = bm + wm + i * 16 + (q << 2) + rg;
            float sc = 1.0f;
            int b2 = 0, node = m;
            if (mode == 2) {
                b2 = m >= NN;
                node = m - b2 * NN;
                sc = dinv[node < NN ? node : NN - 1];
                if (node > 20095) node = 20095;   // pad rows: in-bounds garbage
            }
            #pragma unroll
            for (int j = 0; j < 4; ++j) {
                int n = bn + wn + j * 16 + r;
                float v = acc[i][j][rg] * sc;
                if (mode == 1) {
                    int b = n >> 8;
                    if (m < NN || b) {
                        v += colbias[n];
                        C[((size_t)(b * NN + m)) * 256 + (n & 255)] = f32_to_bf16(v);
                    }
                } else if (mode == 2) {
                    C[(size_t)node * 512 + (b2 << 8) + n] = f32_to_bf16(v);
                } else {
                    C[(size_t)m * N + n] = f32_to_bf16(v);
                }
            }
        }
    }
}

// ---------------- GCN aggregation: one wave per node, both batches, 8-deep MLP -------
// hw: [20096][512] bf16, cols 0..255 = b0, 256..511 = b1, pre-scaled by dinv[src].
__global__ __launch_bounds__(256) void aggregate_i(
    const unsigned short* __restrict__ hw, const int* __restrict__ offs,
    const int* __restrict__ csr, const float* __restrict__ dinv,
    const float* __restrict__ bias, unsigned short* __restrict__ hout,
    const float* __restrict__ w_bp, const float* __restrict__ b_bp,
    float* __restrict__ out)
{
    int n = blockIdx.x * 4 + (threadIdx.x >> 6);   // node 0..19999
    int lane = threadIdx.x & 63;
    const unsigned short* rowp = hw + (lane << 3);

    float acc[8];
    {
        uint4 u = *(const uint4*)(rowp + (size_t)n * 512);
        float4 a = dec4(make_uint2(u.x, u.y)), b = dec4(make_uint2(u.z, u.w));
        acc[0] = a.x; acc[1] = a.y; acc[2] = a.z; acc[3] = a.w;
        acc[4] = b.x; acc[5] = b.y; acc[6] = b.z; acc[7] = b.w;
    }
    int e0 = offs[n], e1 = offs[n + 1];
    int e = e0;
    for (; e + 8 <= e1; e += 8) {
        uint4 u[8];
        #pragma unroll
        for (int t = 0; t < 8; ++t)
            u[t] = *(const uint4*)(rowp + (size_t)csr[e + t] * 512);
        #pragma unroll
        for (int t = 0; t < 8; ++t) {
            float4 a = dec4(make_uint2(u[t].x, u[t].y)), b = dec4(make_uint2(u[t].z, u[t].w));
            acc[0] += a.x; acc[1] += a.y; acc[2] += a.z; acc[3] += a.w;
            acc[4] += b.x; acc[5] += b.y; acc[6] += b.z; acc[7] += b.w;
        }
    }
    if (e + 4 <= e1) {
        uint4 u[4];
        #pragma unroll
        for (int t = 0; t < 4; ++t)
            u[t] = *(const uint4*)(rowp + (size_t)csr[e + t] * 512);
        #pragma unroll
        for (int t = 0; t < 4; ++t) {
            float4 a = dec4(make_uint2(u[t].x, u[t].y)), b = dec4(make_uint2(u[t].z, u[t].w));
            acc[0] += a.x; acc[1] += a.y; acc[2] += a.z; acc[3] += a.w;
            acc[4] += b.x; acc[5] += b.y; acc[6] += b.z; acc[7] += b.w;
        }
        e += 4;
    }
    for (; e < e1; ++e) {
        uint4 u = *(const uint4*)(rowp + (size_t)csr[e] * 512);
        float4 a = dec4(make_uint2(u.x, u.y)), b = dec4(make_uint2(u.z, u.w));
        acc[0] += a.x; acc[1] += a.y; acc[2] += a.z; acc[3] += a.w;
        acc[4] += b.x; acc[5] += b.y; acc[6] += b.z; acc[7] += b.w;
    }

    float dn = dinv[n];
    int s = (lane & 31) << 3;
    float4 bl0 = *(const float4*)(bias + s);
    float4 bl1 = *(const float4*)(bias + s + 4);
    float v[8];
    v[0] = fmaf(dn, acc[0], bl0.x); v[1] = fmaf(dn, acc[1], bl0.y);
    v[2] = fmaf(dn, acc[2], bl0.z); v[3] = fmaf(dn, acc[3], bl0.w);
    v[4] = fmaf(dn, acc[4], bl1.x); v[5] = fmaf(dn, acc[5], bl1.y);
    v[6] = fmaf(dn, acc[6], bl1.z); v[7] = fmaf(dn, acc[7], bl1.w);
    #pragma unroll
    for (int j = 0; j < 8; ++j) v[j] = v[j] > 0.f ? v[j] : 0.01f * v[j];

    int b = lane >> 5;
    if (out) {
        float4 w0 = *(const float4*)(w_bp + s);
        float4 w1 = *(const float4*)(w_bp + s + 4);
        float sum = v[0] * w0.x + v[1] * w0.y + v[2] * w0.z + v[3] * w0.w
                  + v[4] * w1.x + v[5] * w1.y + v[6] * w1.z + v[7] * w1.w;
        #pragma unroll
        for (int off = 16; off; off >>= 1) sum += __shfl_xor(sum, off);
        if ((lane & 31) == 0) out[b * NN + n] = sum + b_bp[0];
    } else {
        uint4 o;
        o.x = ((uint32_t)f32_to_bf16(v[1]) << 16) | f32_to_bf16(v[0]);
        o.y = ((uint32_t)f32_to_bf16(v[3]) << 16) | f32_to_bf16(v[2]);
        o.z = ((uint32_t)f32_to_bf16(v[5]) << 16) | f32_to_bf16(v[4]);
        o.w = ((uint32_t)f32_to_bf16(v[7]) << 16) | f32_to_bf16(v[6]);
        *(uint4*)(hout + ((size_t)(b * NN + n)) * 256 + s) = o;
    }
}

extern "C" void kernel_launch(void* const* d_in, const int* in_sizes, int n_in,
                              void* d_out, int out_size, void* d_ws, size_t ws_size,
                              hipStream_t stream) {
    const float* x     = (const float*)d_in[0];
    const float* nodes = (const float*)d_in[1];
    const int*   eidx  = (const int*)d_in[2];
    const float* Wp    = (const float*)d_in[3];
    const float* bp    = (const float*)d_in[4];
    const float* gcn_W = (const float*)d_in[5];
    const float* gcn_b = (const float*)d_in[6];
    const float* w_bp  = (const float*)d_in[7];
    const float* b_bp  = (const float*)d_in[8];
    const int E = in_sizes[2] / 2;
    const int N = NN;

    char* w = (char*)d_ws;
    auto alloc = [&](size_t bytes) { char* p = w; w += (bytes + 255) & ~(size_t)255; return p; };
    unsigned short* nsum16 = (unsigned short*)alloc((size_t)20096 * 512 * 2); // reused as hw16
    unsigned short* Z      = (unsigned short*)alloc((size_t)20096 * 512 * 2);
    unsigned short* hA     = (unsigned short*)alloc((size_t)40192 * 256 * 2);
    unsigned short* hB     = (unsigned short*)alloc((size_t)40192 * 256 * 2);
    unsigned short* xb  = (unsigned short*)alloc((size_t)512 * 512 * 2);
    unsigned short* Wpb = (unsigned short*)alloc((size_t)512 * 512 * 2);
    unsigned short* WT  = (unsigned short*)alloc((size_t)3 * 256 * 256 * 2);
    float* cvec = (float*)alloc(512 * 4);
    float* dinv = (float*)alloc((size_t)N * 4);
    int*   cnt    = (int*)alloc((size_t)N * 4);
    int*   offs   = (int*)alloc((size_t)(N + 1) * 4);
    int*   cursor = (int*)alloc((size_t)N * 4);
    int*   csr    = (int*)alloc((size_t)E * 4);
    unsigned short* hw16 = nsum16;   // alias: nsum dead after Z GEMM

    hipMemsetAsync(cnt, 0, (size_t)N * 4, stream);
    hipMemsetAsync(cursor, 0, (size_t)N * 4, stream);

    const int cntBlks = (E + 255) / 256;
    prep<<<10480 + cntBlks, 256, 0, stream>>>(nodes, x, Wp, gcn_W, bp, eidx + E,
                                              nsum16, xb, Wpb, WT, cvec, cnt, E);
    scan_kernel<<<1, 1024, 0, stream>>>(cnt, offs, dinv, N);
    fill_kernel<<<cntBlks, 256, 0, stream>>>(eidx, eidx + E, offs, cursor, csr, E);

    // Z[node, f1] = sum_{f2} nsum[node,f2] * Wp[f1,f2]   (BT = Wp as stored)
    mgemm<<<dim3(4, 157), 256, 0, stream>>>(nsum16, Wpb, 512, 512, 0, nullptr, nullptr, Z);
    // h0[node, bs] = sum_{f1} Z[node,f1] * x[bs,f1] + cvec[bs]   (BT = xb as stored)
    mgemm<<<dim3(4, 157), 256, 0, stream>>>(Z, xb, 512, 512, 1, cvec, nullptr, hA);

    unsigned short* hin = hA;
    unsigned short* hout = hB;
    for (int l = 0; l < 3; ++l) {
        mgemm<<<dim3(2, 313), 256, 0, stream>>>(
            hin, WT + (size_t)l * 256 * 256, 256, 256, 2, nullptr, dinv, hw16);
        bool last = (l == 2);
        aggregate_i<<<5000, 256, 0, stream>>>(
            hw16, offs, csr, dinv, gcn_b + l * 256,
            last ? nullptr : hout, w_bp, b_bp,
            last ? (float*)d_out : nullptr);
        unsigned short* t = hin; hin = hout; hout = t;
    }
}

// Round 8
// 393.169 us; speedup vs baseline: 1.0981x; 1.0880x over previous
//
#include <hip/hip_runtime.h>
#include <cstddef>
#include <cstdint>

#define NN 20000
#define SDIM 256

typedef short frag16 __attribute__((ext_vector_type(8)));
typedef float f32x4 __attribute__((ext_vector_type(4)));

__device__ inline unsigned short f32_to_bf16(float f) {
    uint32_t u = __float_as_uint(f);
    u += 0x7FFFu + ((u >> 16) & 1u);
    return (unsigned short)(u >> 16);
}

__device__ inline float4 dec4(uint2 v) {
    float4 r;
    r.x = __uint_as_float(v.x << 16);
    r.y = __uint_as_float(v.x & 0xffff0000u);
    r.z = __uint_as_float(v.y << 16);
    r.w = __uint_as_float(v.y & 0xffff0000u);
    return r;
}

// ===================== fused prep =====================
// sections (256 thr each):
//   [0,64)            T[(b,s),f1] = sum_s' W1[s',s]*x[b,s',f1]  (fp32 tile GEMM -> bf16)
//   [64,10112)        nsum bf16 (20096x512, pad rows zero)
//   [10112,10240)     Wp -> bf16 flat cast
//   [10240,10272)     transpose gcn_W l=1,2 -> WT (bf16)
//   [10272,+cntBlks)  count + fixed-stride CSR fill (stride 64)
__global__ __launch_bounds__(256) void prep(
    const float* __restrict__ nodes, const float* __restrict__ x,
    const float* __restrict__ Wp, const float* __restrict__ gcn_W,
    const int* __restrict__ src, const int* __restrict__ dst,
    unsigned short* __restrict__ nsum16, unsigned short* __restrict__ Wpb,
    unsigned short* __restrict__ WT, unsigned short* __restrict__ Tb,
    int* __restrict__ cnt, int* __restrict__ csr, int E)
{
    __shared__ __align__(16) char shmem[8704];
    const int blk = blockIdx.x, tid = threadIdx.x;

    if (blk < 64) {                          // ---- T section ----
        float* As = (float*)shmem;           // [16][64]  (k, m=s)
        float* Bs = As + 1024;               // [16][64]  (k, n=f1)
        int b = blk >> 5, rem = blk & 31;
        int s0 = (rem >> 3) * 64, f0 = (rem & 7) * 64;
        const float* W1 = gcn_W;             // [s'][s] row-major
        const float* xb = x + (size_t)b * 256 * 512;
        int kk = tid >> 4, c4 = (tid & 15) << 2;
        int tm = tid >> 4, tn = tid & 15;
        float acc[4][4] = {};
        for (int k0 = 0; k0 < 256; k0 += 16) {
            float4 av = *(const float4*)(W1 + (size_t)(k0 + kk) * 256 + s0 + c4);
            float4 bv = *(const float4*)(xb + (size_t)(k0 + kk) * 512 + f0 + c4);
            __syncthreads();
            *(float4*)&As[kk * 64 + c4] = av;
            *(float4*)&Bs[kk * 64 + c4] = bv;
            __syncthreads();
            #pragma unroll
            for (int k = 0; k < 16; ++k) {
                float a[4], bb[4];
                *(float4*)a  = *(const float4*)&As[k * 64 + (tm << 2)];
                *(float4*)bb = *(const float4*)&Bs[k * 64 + (tn << 2)];
                #pragma unroll
                for (int i = 0; i < 4; ++i)
                    #pragma unroll
                    for (int j = 0; j < 4; ++j) acc[i][j] += a[i] * bb[j];
            }
        }
        #pragma unroll
        for (int i = 0; i < 4; ++i) {
            int row = b * 256 + s0 + (tm << 2) + i;
            ushort4 o;
            o.x = f32_to_bf16(acc[i][0]); o.y = f32_to_bf16(acc[i][1]);
            o.z = f32_to_bf16(acc[i][2]); o.w = f32_to_bf16(acc[i][3]);
            *(ushort4*)(Tb + (size_t)row * 512 + f0 + (tn << 2)) = o;
        }
    } else if (blk < 10112) {                // ---- nsum ----
        int idx = (blk - 64) * 256 + tid;    // quad index
        int n = idx >> 7, k4 = (idx & 127) << 2;
        uint2 o;
        if (n < NN) {
            float4 a = *(const float4*)(nodes + (size_t)n * 1024 + k4);
            float4 b = *(const float4*)(nodes + (size_t)n * 1024 + 512 + k4);
            o.x = ((uint32_t)f32_to_bf16(a.y + b.y) << 16) | f32_to_bf16(a.x + b.x);
            o.y = ((uint32_t)f32_to_bf16(a.w + b.w) << 16) | f32_to_bf16(a.z + b.z);
        } else { o.x = 0; o.y = 0; }
        *(uint2*)(nsum16 + (size_t)idx * 4) = o;
    } else if (blk < 10240) {                // ---- Wp cast ----
        size_t off = ((size_t)(blk - 10112) * 256 + tid) * 8;
        float4 a = *(const float4*)(Wp + off);
        float4 b = *(const float4*)(Wp + off + 4);
        uint4 o;
        o.x = ((uint32_t)f32_to_bf16(a.y) << 16) | f32_to_bf16(a.x);
        o.y = ((uint32_t)f32_to_bf16(a.w) << 16) | f32_to_bf16(a.z);
        o.z = ((uint32_t)f32_to_bf16(b.y) << 16) | f32_to_bf16(b.x);
        o.w = ((uint32_t)f32_to_bf16(b.w) << 16) | f32_to_bf16(b.z);
        *(uint4*)(Wpb + off) = o;
    } else if (blk < 10272) {                // ---- WT transpose (l=1,2) ----
        unsigned short (*tsh)[68] = (unsigned short(*)[68])shmem;
        int t = blk - 10240;
        int l = t >> 4, rem = t & 15;
        int c0 = (rem & 3) * 64, r0 = (rem >> 2) * 64;
        const float* inp = gcn_W + (size_t)(l + 1) * 65536;
        unsigned short* outp = WT + (size_t)l * 65536;
        int tx = tid & 15, ty = tid >> 4;
        #pragma unroll
        for (int rr = 0; rr < 4; ++rr) {
            int r = ty * 4 + rr;
            float4 v = *(const float4*)(inp + (size_t)(r0 + r) * 256 + c0 + tx * 4);
            tsh[tx * 4 + 0][r] = f32_to_bf16(v.x);
            tsh[tx * 4 + 1][r] = f32_to_bf16(v.y);
            tsh[tx * 4 + 2][r] = f32_to_bf16(v.z);
            tsh[tx * 4 + 3][r] = f32_to_bf16(v.w);
        }
        __syncthreads();
        #pragma unroll
        for (int cc = 0; cc < 4; ++cc) {
            int c = ty * 4 + cc;
            ushort4 o = *(ushort4*)&tsh[c][tx * 4];
            *(ushort4*)(outp + (size_t)(c0 + c) * 256 + r0 + tx * 4) = o;
        }
    } else {                                 // ---- count + CSR fill ----
        int e = (blk - 10272) * 256 + tid;
        if (e < E) {
            int d = dst[e];
            int pos = atomicAdd(&cnt[d], 1);
            if (pos < 64) csr[(d << 6) + pos] = src[e];
        }
    }
}

// ===================== bf16 MFMA GEMM =====================
// C = A[M,K] @ BT[N,K]^T, bf16 in/out, fp32 accum.
// mode 0: C[m*N+n]=acc. Z-launch uses grid y=158: y==157 blocks compute cb2=2*Tb@bp.
// mode 1: hw1: C[m*512+n] = (acc + cb2[n]) * rsqrt(cnt[m]+1)
// mode 2: N=256, m carries b: node=m-b*NN; C[node*512+(b<<8)+n] = acc*rsqrt(cnt[node]+1)
__global__ __launch_bounds__(256) void mgemm(
    const unsigned short* __restrict__ A, const unsigned short* __restrict__ BT,
    int K, int N, int mode,
    const float* __restrict__ cb2, const int* __restrict__ cnt,
    unsigned short* __restrict__ C,
    float* __restrict__ cb2out, const float* __restrict__ bp,
    const unsigned short* __restrict__ Tb)
{
    if (mode == 0 && (int)blockIdx.y == 157) {   // ---- cb2 side-section ----
        int idx = blockIdx.x * 256 + threadIdx.x;
        if (idx < 512) {
            const unsigned short* tr = Tb + (size_t)idx * 512;
            float s = 0.f;
            for (int k = 0; k < 512; k += 8) {
                uint4 u = *(const uint4*)(tr + k);
                float4 a = dec4(make_uint2(u.x, u.y)), b = dec4(make_uint2(u.z, u.w));
                float4 p0 = *(const float4*)(bp + k);
                float4 p1 = *(const float4*)(bp + k + 4);
                s += a.x * p0.x + a.y * p0.y + a.z * p0.z + a.w * p0.w
                   + b.x * p1.x + b.y * p1.y + b.z * p1.z + b.w * p1.w;
            }
            cb2out[idx] = 2.0f * s;
        }
        return;
    }

    __shared__ __align__(16) unsigned short As[128 * 32];
    __shared__ __align__(16) unsigned short Bs[128 * 32];
    const int bm = blockIdx.y * 128, bn = blockIdx.x * 128;
    const int tid = threadIdx.x;
    const int lane = tid & 63, w = tid >> 6;
    const int wm = (w >> 1) << 6, wn = (w & 1) << 6;
    const int r = lane & 15, q = lane >> 4;

    f32x4 acc[4][4] = {};

    for (int k0 = 0; k0 < K; k0 += 32) {
        __syncthreads();
        #pragma unroll
        for (int t = 0; t < 2; ++t) {
            int c = t * 256 + w * 64 + lane;
            int row = c >> 2, col = (c & 3) << 3;
            __builtin_amdgcn_global_load_lds(
                (const __attribute__((address_space(1))) void*)(A + (size_t)(bm + row) * K + k0 + col),
                (__attribute__((address_space(3))) void*)(As + (size_t)(t * 256 + w * 64) * 8),
                16, 0, 0);
            __builtin_amdgcn_global_load_lds(
                (const __attribute__((address_space(1))) void*)(BT + (size_t)(bn + row) * K + k0 + col),
                (__attribute__((address_space(3))) void*)(Bs + (size_t)(t * 256 + w * 64) * 8),
                16, 0, 0);
        }
        __syncthreads();
        frag16 af[4], bf[4];
        #pragma unroll
        for (int i = 0; i < 4; ++i)
            af[i] = *(const frag16*)(As + ((wm + i * 16 + r) << 5) + (q << 3));
        #pragma unroll
        for (int j = 0; j < 4; ++j)
            bf[j] = *(const frag16*)(Bs + ((wn + j * 16 + r) << 5) + (q << 3));
        #pragma unroll
        for (int i = 0; i < 4; ++i)
            #pragma unroll
            for (int j = 0; j < 4; ++j)
                acc[i][j] = __builtin_amdgcn_mfma_f32_16x16x32_bf16(af[i], bf[j], acc[i][j], 0, 0, 0);
    }

    // C/D layout: col = lane&15 (r), row = q*4 + reg
    #pragma unroll
    for (int i = 0; i < 4; ++i) {
        #pragma unroll
        for (int rg = 0; rg < 4; ++rg) {
            int m = bm + wm + i * 16 + (q << 2) + rg;
            float sc = 1.0f;
            int b2 = 0, node = m;
            if (mode == 1) {
                int nc = m > NN - 1 ? NN - 1 : m;
                sc = rsqrtf((float)cnt[nc] + 1.0f);
            } else if (mode == 2) {
                b2 = m >= NN;
                node = m - b2 * NN;
                int nc = node > NN - 1 ? NN - 1 : node;
                sc = rsqrtf((float)cnt[nc] + 1.0f);
            }
            #pragma unroll
            for (int j = 0; j < 4; ++j) {
                int n = bn + wn + j * 16 + r;
                if (mode == 1) {
                    float v = (acc[i][j][rg] + cb2[n]) * sc;
                    C[(size_t)m * 512 + n] = f32_to_bf16(v);
                } else if (mode == 2) {
                    float v = acc[i][j][rg] * sc;
                    C[(size_t)node * 512 + (b2 << 8) + n] = f32_to_bf16(v);
                } else {
                    C[(size_t)m * N + n] = f32_to_bf16(acc[i][j][rg]);
                }
            }
        }
    }
}

// ===================== GCN aggregation =====================
// hw: [20096][512] bf16, cols 0..255 b0, 256..511 b1, rows pre-scaled by dinv[src].
// fixed-stride CSR: csr[n*64 + e], e < cnt[n].
__global__ __launch_bounds__(256) void aggregate_i(
    const unsigned short* __restrict__ hw, const int* __restrict__ cnt,
    const int* __restrict__ csr, const float* __restrict__ bias,
    unsigned short* __restrict__ hout,
    const float* __restrict__ w_bp, const float* __restrict__ b_bp,
    float* __restrict__ out)
{
    int n = blockIdx.x * 4 + (threadIdx.x >> 6);   // node 0..19999
    int lane = threadIdx.x & 63;
    const unsigned short* rowp = hw + (lane << 3);

    float acc[8];
    {
        uint4 u = *(const uint4*)(rowp + (size_t)n * 512);
        float4 a = dec4(make_uint2(u.x, u.y)), b = dec4(make_uint2(u.z, u.w));
        acc[0] = a.x; acc[1] = a.y; acc[2] = a.z; acc[3] = a.w;
        acc[4] = b.x; acc[5] = b.y; acc[6] = b.z; acc[7] = b.w;
    }
    int deg = cnt[n]; if (deg > 64) deg = 64;
    const int* cp = csr + (n << 6);
    int e = 0;
    for (; e + 8 <= deg; e += 8) {
        uint4 u[8];
        #pragma unroll
        for (int t = 0; t < 8; ++t)
            u[t] = *(const uint4*)(rowp + (size_t)cp[e + t] * 512);
        #pragma unroll
        for (int t = 0; t < 8; ++t) {
            float4 a = dec4(make_uint2(u[t].x, u[t].y)), b = dec4(make_uint2(u[t].z, u[t].w));
            acc[0] += a.x; acc[1] += a.y; acc[2] += a.z; acc[3] += a.w;
            acc[4] += b.x; acc[5] += b.y; acc[6] += b.z; acc[7] += b.w;
        }
    }
    if (e + 4 <= deg) {
        uint4 u[4];
        #pragma unroll
        for (int t = 0; t < 4; ++t)
            u[t] = *(const uint4*)(rowp + (size_t)cp[e + t] * 512);
        #pragma unroll
        for (int t = 0; t < 4; ++t) {
            float4 a = dec4(make_uint2(u[t].x, u[t].y)), b = dec4(make_uint2(u[t].z, u[t].w));
            acc[0] += a.x; acc[1] += a.y; acc[2] += a.z; acc[3] += a.w;
            acc[4] += b.x; acc[5] += b.y; acc[6] += b.z; acc[7] += b.w;
        }
        e += 4;
    }
    for (; e < deg; ++e) {
        uint4 u = *(const uint4*)(rowp + (size_t)cp[e] * 512);
        float4 a = dec4(make_uint2(u.x, u.y)), b = dec4(make_uint2(u.z, u.w));
        acc[0] += a.x; acc[1] += a.y; acc[2] += a.z; acc[3] += a.w;
        acc[4] += b.x; acc[5] += b.y; acc[6] += b.z; acc[7] += b.w;
    }

    float dn = rsqrtf((float)deg + 1.0f);
    int s = (lane & 31) << 3;
    float4 bl0 = *(const float4*)(bias + s);
    float4 bl1 = *(const float4*)(bias + s + 4);
    float v[8];
    v[0] = fmaf(dn, acc[0], bl0.x); v[1] = fmaf(dn, acc[1], bl0.y);
    v[2] = fmaf(dn, acc[2], bl0.z); v[3] = fmaf(dn, acc[3], bl0.w);
    v[4] = fmaf(dn, acc[4], bl1.x); v[5] = fmaf(dn, acc[5], bl1.y);
    v[6] = fmaf(dn, acc[6], bl1.z); v[7] = fmaf(dn, acc[7], bl1.w);
    #pragma unroll
    for (int j = 0; j < 8; ++j) v[j] = v[j] > 0.f ? v[j] : 0.01f * v[j];

    int b = lane >> 5;
    if (out) {
        float4 w0 = *(const float4*)(w_bp + s);
        float4 w1 = *(const float4*)(w_bp + s + 4);
        float sum = v[0] * w0.x + v[1] * w0.y + v[2] * w0.z + v[3] * w0.w
                  + v[4] * w1.x + v[5] * w1.y + v[6] * w1.z + v[7] * w1.w;
        #pragma unroll
        for (int off = 16; off; off >>= 1) sum += __shfl_xor(sum, off);
        if ((lane & 31) == 0) out[b * NN + n] = sum + b_bp[0];
    } else {
        uint4 o;
        o.x = ((uint32_t)f32_to_bf16(v[1]) << 16) | f32_to_bf16(v[0]);
        o.y = ((uint32_t)f32_to_bf16(v[3]) << 16) | f32_to_bf16(v[2]);
        o.z = ((uint32_t)f32_to_bf16(v[5]) << 16) | f32_to_bf16(v[4]);
        o.w = ((uint32_t)f32_to_bf16(v[7]) << 16) | f32_to_bf16(v[6]);
        *(uint4*)(hout + ((size_t)(b * NN + n)) * 256 + s) = o;
    }
}

extern "C" void kernel_launch(void* const* d_in, const int* in_sizes, int n_in,
                              void* d_out, int out_size, void* d_ws, size_t ws_size,
                              hipStream_t stream) {
    const float* x     = (const float*)d_in[0];
    const float* nodes = (const float*)d_in[1];
    const int*   eidx  = (const int*)d_in[2];
    const float* Wp    = (const float*)d_in[3];
    const float* bp    = (const float*)d_in[4];
    const float* gcn_W = (const float*)d_in[5];
    const float* gcn_b = (const float*)d_in[6];
    const float* w_bp  = (const float*)d_in[7];
    const float* b_bp  = (const float*)d_in[8];
    const int E = in_sizes[2] / 2;

    char* w = (char*)d_ws;
    auto alloc = [&](size_t bytes) { char* p = w; w += (bytes + 255) & ~(size_t)255; return p; };
    unsigned short* nsum16 = (unsigned short*)alloc((size_t)20096 * 512 * 2); // reused as hw16
    unsigned short* Z      = (unsigned short*)alloc((size_t)20096 * 512 * 2);
    unsigned short* hA     = (unsigned short*)alloc((size_t)40192 * 256 * 2);
    unsigned short* hB     = (unsigned short*)alloc((size_t)40192 * 256 * 2);
    unsigned short* Wpb = (unsigned short*)alloc((size_t)512 * 512 * 2);
    unsigned short* Tb  = (unsigned short*)alloc((size_t)512 * 512 * 2);
    unsigned short* WT  = (unsigned short*)alloc((size_t)2 * 256 * 256 * 2);
    float* cb2 = (float*)alloc(512 * 4);
    int*   cnt = (int*)alloc((size_t)NN * 4);
    int*   csr = (int*)alloc((size_t)NN * 64 * 4);
    unsigned short* hw16 = nsum16;   // alias: nsum dead after Z GEMM

    hipMemsetAsync(cnt, 0, (size_t)NN * 4, stream);

    const int cntBlks = (E + 255) / 256;
    prep<<<10272 + cntBlks, 256, 0, stream>>>(nodes, x, Wp, gcn_W, eidx, eidx + E,
                                              nsum16, Wpb, WT, Tb, cnt, csr, E);

    // Z[node,f1] = sum_f2 nsum[node,f2]*Wp[f1,f2]; side-blocks (y==157): cb2 = 2*Tb@bp
    mgemm<<<dim3(4, 158), 256, 0, stream>>>(nsum16, Wpb, 512, 512, 0,
                                            nullptr, cnt, Z, cb2, bp, Tb);
    // hw1[node,(b,s)] = (Z@T^T + cb2) * dinv[node]   (layer-1 GEMM fused with h0)
    mgemm<<<dim3(4, 157), 256, 0, stream>>>(Z, Tb, 512, 512, 1,
                                            cb2, cnt, hw16, nullptr, nullptr, nullptr);

    aggregate_i<<<5000, 256, 0, stream>>>(hw16, cnt, csr, gcn_b + 0, hA,
                                          w_bp, b_bp, nullptr);
    mgemm<<<dim3(2, 313), 256, 0, stream>>>(hA, WT, 256, 256, 2,
                                            nullptr, cnt, hw16, nullptr, nullptr, nullptr);
    aggregate_i<<<5000, 256, 0, stream>>>(hw16, cnt, csr, gcn_b + 256, hB,
                                          w_bp, b_bp, nullptr);
    mgemm<<<dim3(2, 313), 256, 0, stream>>>(hB, WT + 65536, 256, 256, 2,
                                            nullptr, cnt, hw16, nullptr, nullptr, nullptr);
    aggregate_i<<<5000, 256, 0, stream>>>(hw16, cnt, csr, gcn_b + 512, nullptr,
                                          w_bp, b_bp, (float*)d_out);
}

// Round 9
// 388.505 us; speedup vs baseline: 1.1113x; 1.0120x over previous
//
#include <hip/hip_runtime.h>
#include <cstddef>
#include <cstdint>

#define NN 20000

typedef short frag16 __attribute__((ext_vector_type(8)));
typedef float f32x4 __attribute__((ext_vector_type(4)));

__device__ inline unsigned short f32_to_bf16(float f) {
    uint32_t u = __float_as_uint(f);
    u += 0x7FFFu + ((u >> 16) & 1u);
    return (unsigned short)(u >> 16);
}

__device__ inline float4 dec4(uint2 v) {
    float4 r;
    r.x = __uint_as_float(v.x << 16);
    r.y = __uint_as_float(v.x & 0xffff0000u);
    r.z = __uint_as_float(v.y << 16);
    r.w = __uint_as_float(v.y & 0xffff0000u);
    return r;
}

// ===================== fused prep =====================
// sections (256 thr each):
//   [0,64)           T[(b,s),f1] = sum_s' W1[s',s]*x[b,s',f1]  (fp32 out)
//   [64,2576)        nsum bf16 (20096x512, pad rows zero), 16 shorts/thread
//   [2576,2608)      transpose gcn_W l=1,2 -> WT (bf16)
//   [2608,2736)      cvec[b,s] = 2*dot(x[b,s,:],bp)
//   [2736,+cntBlks)  edge count + fixed-stride CSR fill (stride 64)
__global__ __launch_bounds__(256) void prep(
    const float* __restrict__ nodes, const float* __restrict__ x,
    const float* __restrict__ gcn_W, const float* __restrict__ bp,
    const int* __restrict__ src, const int* __restrict__ dst,
    unsigned short* __restrict__ nsum16, unsigned short* __restrict__ WT,
    float* __restrict__ Tf, float* __restrict__ cvec,
    int* __restrict__ cnt, int* __restrict__ csr, int E)
{
    __shared__ __align__(16) char shmem[8704];
    const int blk = blockIdx.x, tid = threadIdx.x;

    if (blk < 64) {                          // ---- T section (fp32) ----
        float* As = (float*)shmem;           // [16][64]  (k, m=s)
        float* Bs = As + 1024;               // [16][64]  (k, n=f1)
        int b = blk >> 5, rem = blk & 31;
        int s0 = (rem >> 3) * 64, f0 = (rem & 7) * 64;
        const float* W1 = gcn_W;             // [s'][s] row-major
        const float* xb = x + (size_t)b * 256 * 512;
        int kk = tid >> 4, c4 = (tid & 15) << 2;
        int tm = tid >> 4, tn = tid & 15;
        float acc[4][4] = {};
        for (int k0 = 0; k0 < 256; k0 += 16) {
            float4 av = *(const float4*)(W1 + (size_t)(k0 + kk) * 256 + s0 + c4);
            float4 bv = *(const float4*)(xb + (size_t)(k0 + kk) * 512 + f0 + c4);
            __syncthreads();
            *(float4*)&As[kk * 64 + c4] = av;
            *(float4*)&Bs[kk * 64 + c4] = bv;
            __syncthreads();
            #pragma unroll
            for (int k = 0; k < 16; ++k) {
                float a[4], bb[4];
                *(float4*)a  = *(const float4*)&As[k * 64 + (tm << 2)];
                *(float4*)bb = *(const float4*)&Bs[k * 64 + (tn << 2)];
                #pragma unroll
                for (int i = 0; i < 4; ++i)
                    #pragma unroll
                    for (int j = 0; j < 4; ++j) acc[i][j] += a[i] * bb[j];
            }
        }
        #pragma unroll
        for (int i = 0; i < 4; ++i) {
            int row = b * 256 + s0 + (tm << 2) + i;
            *(float4*)(Tf + (size_t)row * 512 + f0 + (tn << 2)) =
                make_float4(acc[i][0], acc[i][1], acc[i][2], acc[i][3]);
        }
    } else if (blk < 2576) {                 // ---- nsum, 16 shorts/thread ----
        int g = (blk - 64) * 256 + tid;      // [0, 643072)
        int n = g >> 5, c = (g & 31) << 4;   // 32 chunks of 16 per row
        uint4 o0, o1;
        if (n < NN) {
            const float* r0 = nodes + (size_t)n * 1024 + c;
            const float* r1 = r0 + 512;
            float4 a0 = *(const float4*)(r0 + 0),  a1 = *(const float4*)(r0 + 4);
            float4 a2 = *(const float4*)(r0 + 8),  a3 = *(const float4*)(r0 + 12);
            float4 b0 = *(const float4*)(r1 + 0),  b1 = *(const float4*)(r1 + 4);
            float4 b2 = *(const float4*)(r1 + 8),  b3 = *(const float4*)(r1 + 12);
            o0.x = ((uint32_t)f32_to_bf16(a0.y + b0.y) << 16) | f32_to_bf16(a0.x + b0.x);
            o0.y = ((uint32_t)f32_to_bf16(a0.w + b0.w) << 16) | f32_to_bf16(a0.z + b0.z);
            o0.z = ((uint32_t)f32_to_bf16(a1.y + b1.y) << 16) | f32_to_bf16(a1.x + b1.x);
            o0.w = ((uint32_t)f32_to_bf16(a1.w + b1.w) << 16) | f32_to_bf16(a1.z + b1.z);
            o1.x = ((uint32_t)f32_to_bf16(a2.y + b2.y) << 16) | f32_to_bf16(a2.x + b2.x);
            o1.y = ((uint32_t)f32_to_bf16(a2.w + b2.w) << 16) | f32_to_bf16(a2.z + b2.z);
            o1.z = ((uint32_t)f32_to_bf16(a3.y + b3.y) << 16) | f32_to_bf16(a3.x + b3.x);
            o1.w = ((uint32_t)f32_to_bf16(a3.w + b3.w) << 16) | f32_to_bf16(a3.z + b3.z);
        } else {
            o0 = make_uint4(0, 0, 0, 0); o1 = o0;
        }
        *(uint4*)(nsum16 + (size_t)n * 512 + c) = o0;
        *(uint4*)(nsum16 + (size_t)n * 512 + c + 8) = o1;
    } else if (blk < 2608) {                 // ---- WT transpose (l=1,2) ----
        unsigned short (*tsh)[68] = (unsigned short(*)[68])shmem;
        int t = blk - 2576;
        int l = t >> 4, rem = t & 15;
        int c0 = (rem & 3) * 64, r0 = (rem >> 2) * 64;
        const float* inp = gcn_W + (size_t)(l + 1) * 65536;
        unsigned short* outp = WT + (size_t)l * 65536;
        int tx = tid & 15, ty = tid >> 4;
        #pragma unroll
        for (int rr = 0; rr < 4; ++rr) {
            int r = ty * 4 + rr;
            float4 v = *(const float4*)(inp + (size_t)(r0 + r) * 256 + c0 + tx * 4);
            tsh[tx * 4 + 0][r] = f32_to_bf16(v.x);
            tsh[tx * 4 + 1][r] = f32_to_bf16(v.y);
            tsh[tx * 4 + 2][r] = f32_to_bf16(v.z);
            tsh[tx * 4 + 3][r] = f32_to_bf16(v.w);
        }
        __syncthreads();
        #pragma unroll
        for (int cc = 0; cc < 4; ++cc) {
            int c = ty * 4 + cc;
            ushort4 o = *(ushort4*)&tsh[c][tx * 4];
            *(ushort4*)(outp + (size_t)(c0 + c) * 256 + r0 + tx * 4) = o;
        }
    } else if (blk < 2736) {                 // ---- cvec ----
        int row = (blk - 2608) * 4 + (tid >> 6);
        int lane = tid & 63;
        const float* xr = x + (size_t)row * 512;
        float s = 0.f;
        #pragma unroll
        for (int k = 0; k < 512; k += 64) s += xr[k + lane] * bp[k + lane];
        #pragma unroll
        for (int off = 32; off; off >>= 1) s += __shfl_down(s, off);
        if (lane == 0) cvec[row] = 2.0f * s;
    } else {                                 // ---- count + CSR fill ----
        int e = (blk - 2736) * 256 + tid;
        if (e < E) {
            int d = dst[e];
            int pos = atomicAdd(&cnt[d], 1);
            if (pos < 64) csr[(d << 6) + pos] = src[e];
        }
    }
}

// ===================== mid: U = T @ Wp (bf16 out) + cb2 = W1^T . cvec ==============
// grid 66: blk<64 -> 64x64 U tile; blk 64,65 -> cb2
__global__ __launch_bounds__(256) void mid(
    const float* __restrict__ Tf, const float* __restrict__ Wp,
    const float* __restrict__ gcn_W, const float* __restrict__ cvec,
    unsigned short* __restrict__ Ub, float* __restrict__ cb2)
{
    const int blk = blockIdx.x, tid = threadIdx.x;
    if (blk >= 64) {                         // ---- cb2 ----
        int idx = (blk - 64) * 256 + tid;    // [0,512)
        int b = idx >> 8, s = idx & 255;
        float sum = 0.f;
        for (int sp = 0; sp < 256; ++sp)
            sum += gcn_W[(size_t)sp * 256 + s] * cvec[b * 256 + sp];
        cb2[idx] = sum;
        return;
    }
    __shared__ float As[16][68];
    __shared__ float Bs[16][64];
    int bm = (blk >> 3) * 64, bn = (blk & 7) * 64;
    int arow = tid >> 2, acol = (tid & 3) << 2;
    int brow = tid >> 4, bcol = (tid & 15) << 2;
    int tm = tid >> 4, tn = tid & 15;
    float acc[4][4] = {};
    for (int k0 = 0; k0 < 512; k0 += 16) {
        float4 av = *(const float4*)(Tf + (size_t)(bm + arow) * 512 + k0 + acol);
        float4 bv = *(const float4*)(Wp + (size_t)(k0 + brow) * 512 + bn + bcol);
        __syncthreads();
        As[acol + 0][arow] = av.x; As[acol + 1][arow] = av.y;
        As[acol + 2][arow] = av.z; As[acol + 3][arow] = av.w;
        *(float4*)&Bs[brow][bcol] = bv;
        __syncthreads();
        #pragma unroll
        for (int k = 0; k < 16; ++k) {
            float a[4], b[4];
            *(float4*)a = *(const float4*)&As[k][tm << 2];
            *(float4*)b = *(const float4*)&Bs[k][tn << 2];
            #pragma unroll
            for (int i = 0; i < 4; ++i)
                #pragma unroll
                for (int j = 0; j < 4; ++j) acc[i][j] += a[i] * b[j];
        }
    }
    #pragma unroll
    for (int i = 0; i < 4; ++i) {
        int row = bm + (tm << 2) + i;
        ushort4 o;
        o.x = f32_to_bf16(acc[i][0]); o.y = f32_to_bf16(acc[i][1]);
        o.z = f32_to_bf16(acc[i][2]); o.w = f32_to_bf16(acc[i][3]);
        *(ushort4*)(Ub + (size_t)row * 512 + bn + (tn << 2)) = o;
    }
}

// ===================== bf16 MFMA GEMM =====================
// C = A[M,K] @ BT[N,K]^T, bf16 in/out, fp32 accum.
// mode 1: hw1: C[m*512+n] = (acc + cb2[n]) * rsqrt(cnt[m]+1)   (m = node)
// mode 2: N=256, m carries b: node=m-b*NN; C[node*512+(b<<8)+n] = acc*rsqrt(cnt[node]+1)
__global__ __launch_bounds__(256) void mgemm(
    const unsigned short* __restrict__ A, const unsigned short* __restrict__ BT,
    int K, int N, int mode,
    const float* __restrict__ cb2, const int* __restrict__ cnt,
    unsigned short* __restrict__ C)
{
    __shared__ __align__(16) unsigned short As[128 * 32];
    __shared__ __align__(16) unsigned short Bs[128 * 32];
    const int bm = blockIdx.y * 128, bn = blockIdx.x * 128;
    const int tid = threadIdx.x;
    const int lane = tid & 63, w = tid >> 6;
    const int wm = (w >> 1) << 6, wn = (w & 1) << 6;
    const int r = lane & 15, q = lane >> 4;

    f32x4 acc[4][4] = {};

    for (int k0 = 0; k0 < K; k0 += 32) {
        __syncthreads();
        #pragma unroll
        for (int t = 0; t < 2; ++t) {
            int c = t * 256 + w * 64 + lane;
            int row = c >> 2, col = (c & 3) << 3;
            __builtin_amdgcn_global_load_lds(
                (const __attribute__((address_space(1))) void*)(A + (size_t)(bm + row) * K + k0 + col),
                (__attribute__((address_space(3))) void*)(As + (size_t)(t * 256 + w * 64) * 8),
                16, 0, 0);
            __builtin_amdgcn_global_load_lds(
                (const __attribute__((address_space(1))) void*)(BT + (size_t)(bn + row) * K + k0 + col),
                (__attribute__((address_space(3))) void*)(Bs + (size_t)(t * 256 + w * 64) * 8),
                16, 0, 0);
        }
        __syncthreads();
        frag16 af[4], bf[4];
        #pragma unroll
        for (int i = 0; i < 4; ++i)
            af[i] = *(const frag16*)(As + ((wm + i * 16 + r) << 5) + (q << 3));
        #pragma unroll
        for (int j = 0; j < 4; ++j)
            bf[j] = *(const frag16*)(Bs + ((wn + j * 16 + r) << 5) + (q << 3));
        #pragma unroll
        for (int i = 0; i < 4; ++i)
            #pragma unroll
            for (int j = 0; j < 4; ++j)
                acc[i][j] = __builtin_amdgcn_mfma_f32_16x16x32_bf16(af[i], bf[j], acc[i][j], 0, 0, 0);
    }

    // C/D layout: col = lane&15 (r), row = q*4 + reg
    #pragma unroll
    for (int i = 0; i < 4; ++i) {
        #pragma unroll
        for (int rg = 0; rg < 4; ++rg) {
            int m = bm + wm + i * 16 + (q << 2) + rg;
            float sc;
            int b2 = 0, node = m;
            if (mode == 1) {
                int nc = m > NN - 1 ? NN - 1 : m;
                sc = rsqrtf((float)cnt[nc] + 1.0f);
            } else {
                b2 = m >= NN;
                node = m - b2 * NN;
                int nc = node > NN - 1 ? NN - 1 : node;
                sc = rsqrtf((float)cnt[nc] + 1.0f);
                if (node > 20095) node = 20095;     // pad rows: stay in-buffer
            }
            #pragma unroll
            for (int j = 0; j < 4; ++j) {
                int n = bn + wn + j * 16 + r;
                if (mode == 1) {
                    float v = (acc[i][j][rg] + cb2[n]) * sc;
                    C[(size_t)m * 512 + n] = f32_to_bf16(v);
                } else {
                    float v = acc[i][j][rg] * sc;
                    C[(size_t)node * 512 + (b2 << 8) + n] = f32_to_bf16(v);
                }
            }
        }
    }
}

// ===================== GCN aggregation (batch-sliced, 2 passes) =====================
// hw: [20096][512] bf16, cols 0..255 b0, 256..511 b1, rows pre-scaled by dinv[src].
// grid (5000, 2): y = batch (dispatch x-first => passes temporally separated).
// One wave per node; uint2 (8B) slice loads; int4 csr loads.
__global__ __launch_bounds__(256) void aggregate_s(
    const unsigned short* __restrict__ hw, const int* __restrict__ cnt,
    const int* __restrict__ csr, const float* __restrict__ bias,
    unsigned short* __restrict__ hout,
    const float* __restrict__ w_bp, const float* __restrict__ b_bp,
    float* __restrict__ out)
{
    int n = blockIdx.x * 4 + (threadIdx.x >> 6);   // node 0..19999
    int b = blockIdx.y;
    int lane = threadIdx.x & 63;
    const unsigned short* rowp = hw + (b << 8) + (lane << 2);

    float4 acc = dec4(*(const uint2*)(rowp + (size_t)n * 512));   // self loop
    int deg = cnt[n]; if (deg > 64) deg = 64;
    const int* cp = csr + (n << 6);
    int e = 0;
    for (; e + 8 <= deg; e += 8) {
        int4 c0 = *(const int4*)(cp + e);
        int4 c1 = *(const int4*)(cp + e + 4);
        uint2 u0 = *(const uint2*)(rowp + (size_t)c0.x * 512);
        uint2 u1 = *(const uint2*)(rowp + (size_t)c0.y * 512);
        uint2 u2 = *(const uint2*)(rowp + (size_t)c0.z * 512);
        uint2 u3 = *(const uint2*)(rowp + (size_t)c0.w * 512);
        uint2 u4 = *(const uint2*)(rowp + (size_t)c1.x * 512);
        uint2 u5 = *(const uint2*)(rowp + (size_t)c1.y * 512);
        uint2 u6 = *(const uint2*)(rowp + (size_t)c1.z * 512);
        uint2 u7 = *(const uint2*)(rowp + (size_t)c1.w * 512);
        float4 f0 = dec4(u0), f1 = dec4(u1), f2 = dec4(u2), f3 = dec4(u3);
        float4 f4 = dec4(u4), f5 = dec4(u5), f6 = dec4(u6), f7 = dec4(u7);
        acc.x += ((f0.x + f1.x) + (f2.x + f3.x)) + ((f4.x + f5.x) + (f6.x + f7.x));
        acc.y += ((f0.y + f1.y) + (f2.y + f3.y)) + ((f4.y + f5.y) + (f6.y + f7.y));
        acc.z += ((f0.z + f1.z) + (f2.z + f3.z)) + ((f4.z + f5.z) + (f6.z + f7.z));
        acc.w += ((f0.w + f1.w) + (f2.w + f3.w)) + ((f4.w + f5.w) + (f6.w + f7.w));
    }
    for (; e < deg; ++e) {
        float4 f = dec4(*(const uint2*)(rowp + (size_t)cp[e] * 512));
        acc.x += f.x; acc.y += f.y; acc.z += f.z; acc.w += f.w;
    }

    float dn = rsqrtf((float)deg + 1.0f);
    int s = lane << 2;
    float4 bl = *(const float4*)(bias + s);
    float4 v;
    v.x = fmaf(dn, acc.x, bl.x); v.y = fmaf(dn, acc.y, bl.y);
    v.z = fmaf(dn, acc.z, bl.z); v.w = fmaf(dn, acc.w, bl.w);
    v.x = v.x > 0.f ? v.x : 0.01f * v.x;
    v.y = v.y > 0.f ? v.y : 0.01f * v.y;
    v.z = v.z > 0.f ? v.z : 0.01f * v.z;
    v.w = v.w > 0.f ? v.w : 0.01f * v.w;

    if (out) {
        float4 w4 = *(const float4*)(w_bp + s);
        float sum = v.x * w4.x + v.y * w4.y + v.z * w4.z + v.w * w4.w;
        #pragma unroll
        for (int off = 32; off; off >>= 1) sum += __shfl_xor(sum, off);
        if (lane == 0) out[b * NN + n] = sum + b_bp[0];
    } else {
        uint2 o;
        o.x = ((uint32_t)f32_to_bf16(v.y) << 16) | f32_to_bf16(v.x);
        o.y = ((uint32_t)f32_to_bf16(v.w) << 16) | f32_to_bf16(v.z);
        *(uint2*)(hout + ((size_t)(b * NN + n)) * 256 + s) = o;
    }
}

extern "C" void kernel_launch(void* const* d_in, const int* in_sizes, int n_in,
                              void* d_out, int out_size, void* d_ws, size_t ws_size,
                              hipStream_t stream) {
    const float* x     = (const float*)d_in[0];
    const float* nodes = (const float*)d_in[1];
    const int*   eidx  = (const int*)d_in[2];
    const float* Wp    = (const float*)d_in[3];
    const float* bp    = (const float*)d_in[4];
    const float* gcn_W = (const float*)d_in[5];
    const float* gcn_b = (const float*)d_in[6];
    const float* w_bp  = (const float*)d_in[7];
    const float* b_bp  = (const float*)d_in[8];
    const int E = in_sizes[2] / 2;

    char* w = (char*)d_ws;
    auto alloc = [&](size_t bytes) { char* p = w; w += (bytes + 255) & ~(size_t)255; return p; };
    unsigned short* nsum16 = (unsigned short*)alloc((size_t)20096 * 512 * 2);
    unsigned short* hw16   = (unsigned short*)alloc((size_t)20096 * 512 * 2);
    unsigned short* hA     = (unsigned short*)alloc((size_t)40192 * 256 * 2);
    unsigned short* hB     = (unsigned short*)alloc((size_t)40192 * 256 * 2);
    float* Tf  = (float*)alloc((size_t)512 * 512 * 4);
    unsigned short* Ub = (unsigned short*)alloc((size_t)512 * 512 * 2);
    unsigned short* WT = (unsigned short*)alloc((size_t)2 * 256 * 256 * 2);
    float* cvec = (float*)alloc(512 * 4);
    float* cb2  = (float*)alloc(512 * 4);
    int*   cnt  = (int*)alloc((size_t)NN * 4);
    int*   csr  = (int*)alloc((size_t)NN * 64 * 4);

    hipMemsetAsync(cnt, 0, (size_t)NN * 4, stream);

    const int cntBlks = (E + 255) / 256;
    prep<<<2736 + cntBlks, 256, 0, stream>>>(nodes, x, gcn_W, bp, eidx, eidx + E,
                                             nsum16, WT, Tf, cvec, cnt, csr, E);
    mid<<<66, 256, 0, stream>>>(Tf, Wp, gcn_W, cvec, Ub, cb2);

    // hw1[node,(b,s)] = (nsum @ U^T + cb2) * dinv[node]
    mgemm<<<dim3(4, 157), 256, 0, stream>>>(nsum16, Ub, 512, 512, 1, cb2, cnt, hw16);

    aggregate_s<<<dim3(5000, 2), 256, 0, stream>>>(hw16, cnt, csr, gcn_b + 0, hA,
                                                   w_bp, b_bp, nullptr);
    mgemm<<<dim3(2, 313), 256, 0, stream>>>(hA, WT, 256, 256, 2, nullptr, cnt, hw16);
    aggregate_s<<<dim3(5000, 2), 256, 0, stream>>>(hw16, cnt, csr, gcn_b + 256, hB,
                                                   w_bp, b_bp, nullptr);
    mgemm<<<dim3(2, 313), 256, 0, stream>>>(hB, WT + 65536, 256, 256, 2, nullptr, cnt, hw16);
    aggregate_s<<<dim3(5000, 2), 256, 0, stream>>>(hw16, cnt, csr, gcn_b + 512, nullptr,
                                                   w_bp, b_bp, (float*)d_out);
}